// Round 9
// baseline (274.965 us; speedup 1.0000x reference)
//
#include <hip/hip_runtime.h>
#include <stdint.h>

#define B_   8
#define N_   2048
#define C_   128
#define EPS_ 0.1f

typedef __attribute__((ext_vector_type(8))) short short8;
typedef __attribute__((ext_vector_type(4))) float f32x4;

__device__ __forceinline__ unsigned short f2bf(float f) {
    union { float f; uint32_t u; } v; v.f = f;
    uint32_t u = v.u + 0x7FFF + ((v.u >> 16) & 1);   // RNE (inputs are finite)
    return (unsigned short)(u >> 16);
}

// ---------------- kernel 0: Wt[o][k] = bf16(W[k][o]) ----------------
__global__ __launch_bounds__(128) void k_wt(const float* __restrict__ W,
                                            unsigned short* __restrict__ Wt) {
    const int o = blockIdx.x, k = threadIdx.x;
    Wt[o * C_ + k] = f2bf(W[k * C_ + o]);
}

// ---- kernel 1: ht[b][o][j]=bf16(h), al/ar = h . w_att (MFMA x@W) ----
__global__ __launch_bounds__(256) void k_h(
    const float* __restrict__ x, const unsigned short* __restrict__ Wt,
    const float* __restrict__ wl, const float* __restrict__ wr,
    unsigned short* __restrict__ ht, float* __restrict__ al, float* __restrict__ ar)
{
    const int b    = blockIdx.x >> 5;
    const int i0   = (blockIdx.x & 31) * 64;
    const int t    = threadIdx.x;
    const int lane = t & 63;
    const int wid  = t >> 6;

    // [row][k] bf16, XOR-swizzled in 16B units: u' = u ^ (row&15)
    __shared__ __align__(16) unsigned short xs[64 * 128];
    __shared__ __align__(16) unsigned short ws[128 * 128];

    // stage x (fp32 -> bf16)
    #pragma unroll
    for (int p = 0; p < 4; ++p) {
        const int s = p * 256 + t, row = s >> 4, u = s & 15;
        const float* gp = x + ((size_t)(b * N_ + i0 + row) * C_ + u * 8);
        float4 f0 = *(const float4*)gp;
        float4 f1 = *(const float4*)(gp + 4);
        short8 tv;
        tv[0] = (short)f2bf(f0.x); tv[1] = (short)f2bf(f0.y);
        tv[2] = (short)f2bf(f0.z); tv[3] = (short)f2bf(f0.w);
        tv[4] = (short)f2bf(f1.x); tv[5] = (short)f2bf(f1.y);
        tv[6] = (short)f2bf(f1.z); tv[7] = (short)f2bf(f1.w);
        *(short8*)&xs[row * 128 + (u ^ (row & 15)) * 8] = tv;
    }
    // stage Wt (already bf16)
    #pragma unroll
    for (int p = 0; p < 8; ++p) {
        const int s = p * 256 + t, o = s >> 4, u = s & 15;
        int4 v = *(const int4*)(Wt + o * C_ + u * 8);
        *(int4*)&ws[o * 128 + (u ^ (o & 15)) * 8] = v;
    }
    __syncthreads();

    const int m0 = wid * 16, lr = lane & 15, q = lane >> 4;
    f32x4 acc[8];
    #pragma unroll
    for (int i = 0; i < 8; ++i) acc[i] = (f32x4){0.f, 0.f, 0.f, 0.f};

    #pragma unroll
    for (int s = 0; s < 4; ++s) {
        const int m = m0 + lr;
        short8 af = *(const short8*)&xs[m * 128 + ((s * 4 + q) ^ (m & 15)) * 8];
        #pragma unroll
        for (int tt = 0; tt < 8; ++tt) {
            const int o = tt * 16 + lr;
            short8 bf = *(const short8*)&ws[o * 128 + ((s * 4 + q) ^ (o & 15)) * 8];
            acc[tt] = __builtin_amdgcn_mfma_f32_16x16x32_bf16(af, bf, acc[tt], 0, 0, 0);
        }
    }

    // epilogue: ht (transposed bf16) + al/ar partials
    float pl[4] = {0.f, 0.f, 0.f, 0.f}, pr[4] = {0.f, 0.f, 0.f, 0.f};
    const int j0 = i0 + m0 + q * 4;     // D rows = j index, 4 consecutive
    #pragma unroll
    for (int tt = 0; tt < 8; ++tt) {
        const int o = tt * 16 + lr;
        const float wlv = wl[o], wrv = wr[o];
        unsigned int lo = (unsigned int)f2bf(acc[tt][0]) | ((unsigned int)f2bf(acc[tt][1]) << 16);
        unsigned int hi = (unsigned int)f2bf(acc[tt][2]) | ((unsigned int)f2bf(acc[tt][3]) << 16);
        uint2 u2; u2.x = lo; u2.y = hi;
        *(uint2*)&ht[((size_t)(b * C_ + o)) * N_ + j0] = u2;
        #pragma unroll
        for (int r = 0; r < 4; ++r) {
            pl[r] = fmaf(acc[tt][r], wlv, pl[r]);
            pr[r] = fmaf(acc[tt][r], wrv, pr[r]);
        }
    }
    #pragma unroll
    for (int msk = 1; msk < 16; msk <<= 1) {
        #pragma unroll
        for (int r = 0; r < 4; ++r) {
            pl[r] += __shfl_xor(pl[r], msk, 64);
            pr[r] += __shfl_xor(pr[r], msk, 64);
        }
    }
    if (lr == 0) {
        #pragma unroll
        for (int r = 0; r < 4; ++r) {
            al[b * N_ + j0 + r] = pl[r];
            ar[b * N_ + j0 + r] = pr[r];
        }
    }
}

// ---- kernel 2: out = mask(tanh(ar_i*al_j)) @ h + eps*x0  (MFMA) ----
// v9 = v8 with the UB fixed: v7/v8 read av[4..7]/lv[4..7] past the end of
// a single local int4/float4 (stack OOB -> scratch fault -> the two HSA
// aborts). Loads now go into proper 2-element arrays indexed only with
// compile-time constants.
// TLP design: 1024 blocks x 256 thr (4 waves). Each block owns a 16-row x
// full-C output tile; the 4 waves j-split the K dimension (wave w: chunks
// w*8..w*8+7) => tanh & adj computed/fetched exactly once, NO per-chunk
// barriers, NO cross-wave deps in the main loop. Partials reduced through
// LDS once per block (single barrier). 16 waves/CU hide load latency by
// wave switching — no reliance on compiler-kept register prefetch
// (R2-R6: it always gets sunk). b = blockIdx&7 pins batches to XCDs.
__global__ __launch_bounds__(256) void k_out(
    const int* __restrict__ adj, const unsigned short* __restrict__ ht,
    const float* __restrict__ al, const float* __restrict__ ar,
    const float* __restrict__ x0, float* __restrict__ out)
{
    const int b    = blockIdx.x & 7;          // XCD-local batch
    const int i0   = (blockIdx.x >> 3) * 16;  // row tile
    const int t    = threadIdx.x;
    const int lane = t & 63;
    const int wid  = t >> 6;                  // 0..3 (j-split)
    const int lr   = lane & 15, q = lane >> 4;

    // reduction buffer: [wave][row][col], col padded 128->132 (row = 528 B,
    // 16B-aligned; breaks power-of-2 bank stride)
    __shared__ __align__(16) float red[4][16][132];   // 33 KB

    const float arv = ar[b * N_ + i0 + lr];
    const float tl  = 2.f * arv;

    const int*            adjp = adj + ((size_t)(b * N_) + i0 + lr) * N_ + q * 8;
    const float*          alp  = al + b * N_ + q * 8;
    const unsigned short* htp  = ht + ((size_t)(b * C_) + lr) * N_ + q * 8;

    f32x4 acc[8];
    #pragma unroll
    for (int i = 0; i < 8; ++i) acc[i] = (f32x4){0.f, 0.f, 0.f, 0.f};

    // wave wid processes j-chunks [wid*8, wid*8+8), chunk = 64 j
    #pragma unroll 1
    for (int k = 0; k < 8; ++k) {
        const int j0 = (wid * 8 + k) * 64;
        #pragma unroll
        for (int s2 = 0; s2 < 2; ++s2) {
            const int jo = j0 + s2 * 32;
            int4 a01[2];
            a01[0] = *(const int4*)(adjp + jo);
            a01[1] = *(const int4*)(adjp + jo + 4);
            float4 l01[2];
            l01[0] = *(const float4*)(alp + jo);
            l01[1] = *(const float4*)(alp + jo + 4);
            const int*   av = (const int*)a01;
            const float* lv = (const float*)l01;
            short8 af;
            #pragma unroll
            for (int e = 0; e < 8; ++e) {
                float ex = __expf(tl * lv[e]);
                float th = 1.f - 2.f * __builtin_amdgcn_rcpf(ex + 1.f);
                af[e] = av[e] ? (short)f2bf(th) : (short)0;
            }
            #pragma unroll
            for (int tt = 0; tt < 8; ++tt) {
                short8 bf = *(const short8*)(htp + (size_t)(tt * 16) * N_ + jo);
                acc[tt] = __builtin_amdgcn_mfma_f32_16x16x32_bf16(af, bf, acc[tt], 0, 0, 0);
            }
        }
    }

    // ---- cross-wave reduction (one barrier per block) ----
    #pragma unroll
    for (int tt = 0; tt < 8; ++tt)
        #pragma unroll
        for (int r = 0; r < 4; ++r)
            red[wid][q * 4 + r][tt * 16 + lr] = acc[tt][r];
    __syncthreads();

    // each thread: 8 consecutive floats of the 16x128 tile
    const int row = t >> 4;            // 0..15
    const int c0  = (t & 15) * 8;      // 0..120
    float s[8];
    #pragma unroll
    for (int e = 0; e < 8; ++e) s[e] = 0.f;
    #pragma unroll
    for (int w = 0; w < 4; ++w) {
        float4 v0 = *(const float4*)&red[w][row][c0];
        float4 v1 = *(const float4*)&red[w][row][c0 + 4];
        s[0] += v0.x; s[1] += v0.y; s[2] += v0.z; s[3] += v0.w;
        s[4] += v1.x; s[5] += v1.y; s[6] += v1.z; s[7] += v1.w;
    }
    const size_t idx = ((size_t)(b * N_) + i0 + row) * C_ + c0;
    float4 xa = *(const float4*)(x0 + idx);
    float4 xb = *(const float4*)(x0 + idx + 4);
    float4 o0, o1;
    o0.x = s[0] + EPS_ * xa.x; o0.y = s[1] + EPS_ * xa.y;
    o0.z = s[2] + EPS_ * xa.z; o0.w = s[3] + EPS_ * xa.w;
    o1.x = s[4] + EPS_ * xb.x; o1.y = s[5] + EPS_ * xb.y;
    o1.z = s[6] + EPS_ * xb.z; o1.w = s[7] + EPS_ * xb.w;
    *(float4*)(out + idx)     = o0;
    *(float4*)(out + idx + 4) = o1;
}

extern "C" void kernel_launch(void* const* d_in, const int* in_sizes, int n_in,
                              void* d_out, int out_size, void* d_ws, size_t ws_size,
                              hipStream_t stream) {
    const float* x   = (const float*)d_in[0];
    const float* x0  = (const float*)d_in[1];
    const int*   adj = (const int*)d_in[2];
    const float* W   = (const float*)d_in[3];
    const float* wl  = (const float*)d_in[4];
    const float* wr  = (const float*)d_in[5];
    float* out = (float*)d_out;

    unsigned short* ht = (unsigned short*)d_ws;                      // 4 MB
    float* al = (float*)((char*)d_ws + (size_t)B_ * C_ * N_ * 2);
    float* ar = al + B_ * N_;
    unsigned short* Wt = (unsigned short*)(ar + B_ * N_);            // 32 KB

    k_wt <<<C_,             C_,  0, stream>>>(W, Wt);
    k_h  <<<B_ * (N_ / 64), 256, 0, stream>>>(x, Wt, wl, wr, ht, al, ar);
    k_out<<<B_ * (N_ / 16), 256, 0, stream>>>(adj, ht, al, ar, x0, out);
}